// Round 1
// 1017.802 us; speedup vs baseline: 1.1844x; 1.1844x over previous
//
#include <hip/hip_runtime.h>

typedef __attribute__((ext_vector_type(8))) short short8;   // 8 bf16 = 4 VGPRs (MFMA A/B frag)
typedef __attribute__((ext_vector_type(4))) float f32x4;    // MFMA C/D frag

#define F   256
#define SH  264   // LDS row stride in bf16 units: 528 B, 16B-aligned, <=2-way bank aliasing

__device__ __forceinline__ short f2bf(float f) {
    union { float f; unsigned u; } v; v.f = f;
    unsigned r = (v.u + 0x7fffu + ((v.u >> 16) & 1u)) >> 16;   // RTNE
    return (short)r;
}
__device__ __forceinline__ float bf2f(short s) {
    union { float f; unsigned u; } v; v.u = ((unsigned)(unsigned short)s) << 16;
    return v.f;
}
__device__ __forceinline__ float sigm(float x) {
    return __builtin_amdgcn_rcpf(1.f + __builtin_amdgcn_exp2f(-1.442695041f * x));
}
__device__ __forceinline__ float tanhx(float x) {
    return 1.f - 2.f * __builtin_amdgcn_rcpf(1.f + __builtin_amdgcn_exp2f(2.885390082f * x));
}
__device__ __forceinline__ f32x4 splat4(float v) {
    f32x4 r; r[0] = v; r[1] = v; r[2] = v; r[3] = v; return r;
}

// ---------------------------------------------------------------------------
// Pack kernel: swizzle W_hh, W_ih (hi+lo split), W_out into MFMA-B-fragment
// order, now WAVE-CONTIGUOUS: each wave's per-step stream is one sequential
// 64 KB block.  whh/wih layout: [w][kt][i][lane][8], i.e. short index
//   ((w*8 + kt)*8 + i)*512 + lane*8
// where nt = (i>>1)*16 + 2w + (i&1)  (so w = (nt&15)>>1, i = (nt>>4)*2+(nt&1)).
// wout layout: [w][kt][s][lane][8]:  ((w*8 + kt)*2 + s)*512 + lane*8,
// where nt = 2w + s.
// ---------------------------------------------------------------------------
__global__ void pack_kernel(const float* __restrict__ Whh, const float* __restrict__ Wih,
                            const float* __restrict__ Wout,
                            short* __restrict__ whh_p, short* __restrict__ wih_hi,
                            short* __restrict__ wih_lo, short* __restrict__ wout_p)
{
    int idx = blockIdx.x * blockDim.x + threadIdx.x;
    if (idx < 64 * 8 * 64) {                       // W_hh + W_ih: 64 n-tiles x 8 k-tiles x 64 lanes
        int lane = idx & 63, kt = (idx >> 6) & 7, nt = idx >> 9;
        int n = nt * 16 + (lane & 15);
        int k = kt * 32 + (lane >> 4) * 8;
        int w = (nt & 15) >> 1;
        int i = ((nt >> 4) << 1) | (nt & 1);
        int dst = (((w * 8 + kt) * 8 + i) * 64 + lane) * 8;
        const float* s1 = Whh + n * F + k;
        const float* s2 = Wih + n * F + k;
        #pragma unroll
        for (int j = 0; j < 8; j++) {
            whh_p[dst + j] = f2bf(s1[j]);
            float v = s2[j];
            short hi = f2bf(v);
            wih_hi[dst + j] = hi;
            wih_lo[dst + j] = f2bf(v - bf2f(hi));
        }
    } else {
        int i2 = idx - 64 * 8 * 64;
        if (i2 < 16 * 8 * 64) {                    // W_out: 16 n-tiles
            int lane = i2 & 63, kt = (i2 >> 6) & 7, nt = i2 >> 9;
            int n = nt * 16 + (lane & 15);
            int k = kt * 32 + (lane >> 4) * 8;
            int w = nt >> 1, s = nt & 1;
            int dst = (((w * 8 + kt) * 2 + s) * 64 + lane) * 8;
            const float* sp = Wout + n * F + k;
            #pragma unroll
            for (int j = 0; j < 8; j++) wout_p[dst + j] = f2bf(sp[j]);
        }
    }
}

// Accumulate acc[i][mt] += A(h in LDS) x B(packed W, wave-contiguous).
// Wp must be pre-offset to the wave's 32768-short slice.
// Software-pipelined: kt-group k+1's 8 b-frags are in flight (global loads)
// while kt-group k's 16 MFMAs execute.  All buffer indices static (full unroll).
__device__ __forceinline__ void gate_mm(f32x4 (&acc)[8][2], const short* __restrict__ Wp,
                                        const short* hb, int lane)
{
    const int l15 = lane & 15, quad = lane >> 4;
    const short* bp = Wp + lane * 8;
    short8 be[8], bod[8];
    #pragma unroll
    for (int i = 0; i < 8; i++) be[i] = *(const short8*)(bp + i * 512);     // kt=0
    #pragma unroll
    for (int kt = 0; kt < 8; kt += 2) {
        // prefetch odd group kt+1 while even group kt computes
        #pragma unroll
        for (int i = 0; i < 8; i++)
            bod[i] = *(const short8*)(bp + (kt + 1) * 4096 + i * 512);
        short8 a0 = *(const short8*)(hb + l15 * SH + kt * 32 + quad * 8);
        short8 a1 = *(const short8*)(hb + (16 + l15) * SH + kt * 32 + quad * 8);
        #pragma unroll
        for (int i = 0; i < 8; i++) {
            acc[i][0] = __builtin_amdgcn_mfma_f32_16x16x32_bf16(a0, be[i], acc[i][0], 0, 0, 0);
            acc[i][1] = __builtin_amdgcn_mfma_f32_16x16x32_bf16(a1, be[i], acc[i][1], 0, 0, 0);
        }
        // prefetch even group kt+2 while odd group kt+1 computes
        if (kt + 2 < 8) {
            #pragma unroll
            for (int i = 0; i < 8; i++)
                be[i] = *(const short8*)(bp + (kt + 2) * 4096 + i * 512);
        }
        a0 = *(const short8*)(hb + l15 * SH + (kt + 1) * 32 + quad * 8);
        a1 = *(const short8*)(hb + (16 + l15) * SH + (kt + 1) * 32 + quad * 8);
        #pragma unroll
        for (int i = 0; i < 8; i++) {
            acc[i][0] = __builtin_amdgcn_mfma_f32_16x16x32_bf16(a0, bod[i], acc[i][0], 0, 0, 0);
            acc[i][1] = __builtin_amdgcn_mfma_f32_16x16x32_bf16(a1, bod[i], acc[i][1], 0, 0, 0);
        }
    }
}

// ---------------------------------------------------------------------------
// Fused LSTM: 128 blocks x 512 threads (8 waves).  Block owns 32 rows for all
// T steps.  x_proj: split-bf16 (fp32-exact) in 64 VGPRs.  c fp32 in regs.
// h -> LDS bf16 each step.  W_out resident in LDS (loaded once).  Output
// stores non-temporal so the 210 MB stream doesn't evict weights from L2/L3.
// ---------------------------------------------------------------------------
__global__ __launch_bounds__(512, 2)
void lstm_fused(const float* __restrict__ x, const float* __restrict__ b_ih,
                const float* __restrict__ b_hh, const float* __restrict__ c0,
                const float* __restrict__ b_out,
                const short* __restrict__ whh_p, const short* __restrict__ wih_hi,
                const short* __restrict__ wih_lo, const short* __restrict__ wout_p,
                const int* __restrict__ seqlen, float* __restrict__ out)
{
    __shared__ short hbuf[32 * SH];        //  16.9 KB
    __shared__ short wout_lds[65536];      // 128.0 KB  (total 144.9 KB <= 160 KB)
    const int T    = *seqlen;
    const int tid  = threadIdx.x;
    const int lane = tid & 63;
    const int w    = tid >> 6;        // wave 0..7
    const int l15  = lane & 15;
    const int quad = lane >> 4;
    const int row0 = blockIdx.x * 32;

    const short* whh_w    = whh_p  + (w << 15);   // per-wave 32768-short slice
    const short* wih_hi_w = wih_hi + (w << 15);
    const short* wih_lo_w = wih_lo + (w << 15);

    // ---- stage this wave's W_out slice into LDS (own region: no barrier) ----
    {
        const short* src = wout_p + w * 8192 + lane * 8;
        short*       dst = wout_lds + w * 8192 + lane * 8;
        #pragma unroll
        for (int q = 0; q < 16; q++)
            *(short8*)(dst + q * 512) = *(const short8*)(src + q * 512);
    }

    // ---- load this block's 32 x-rows (fp32, coalesced dwordx4) ----
    const int xr = tid >> 4;          // 0..31
    const int xc = (tid & 15) * 16;   // 0..240
    float xv[16];
    {
        const float* xp = x + (size_t)(row0 + xr) * F + xc;
        #pragma unroll
        for (int j = 0; j < 16; j++) xv[j] = xp[j];
    }

    // ---- x_proj = x @ W_ih^T + b_ih + b_hh, fp32-accurate via 3-term split bf16 ----
    f32x4 xpj[8][2];
    #pragma unroll
    for (int i = 0; i < 8; i++) { xpj[i][0] = splat4(0.f); xpj[i][1] = splat4(0.f); }

    // stage x_lo, accumulate lo x Wih_hi
    #pragma unroll
    for (int j = 0; j < 16; j++) {
        short hi = f2bf(xv[j]);
        hbuf[xr * SH + xc + j] = f2bf(xv[j] - bf2f(hi));
    }
    __syncthreads();
    gate_mm(xpj, wih_hi_w, hbuf, lane);
    __syncthreads();
    // stage x_hi (stays in LDS as h_0), accumulate hi x Wih_hi + hi x Wih_lo
    #pragma unroll
    for (int j = 0; j < 16; j++) hbuf[xr * SH + xc + j] = f2bf(xv[j]);
    __syncthreads();
    gate_mm(xpj, wih_hi_w, hbuf, lane);
    gate_mm(xpj, wih_lo_w, hbuf, lane);

    // biases (b_ih + b_hh), per-gate column
    #pragma unroll
    for (int i = 0; i < 8; i++) {
        int nt = (i >> 1) * 16 + 2 * w + (i & 1);
        float bias = b_ih[nt * 16 + l15] + b_hh[nt * 16 + l15];
        #pragma unroll
        for (int mt = 0; mt < 2; mt++)
            #pragma unroll
            for (int r = 0; r < 4; r++) xpj[i][mt][r] += bias;
    }

    // cell state init (c0 broadcast over rows) + output bias
    float cst[2][2][4];
    float bo[2];
    #pragma unroll
    for (int s = 0; s < 2; s++) {
        float cv = c0[w * 32 + s * 16 + l15];
        bo[s]    = b_out[w * 32 + s * 16 + l15];
        #pragma unroll
        for (int mt = 0; mt < 2; mt++)
            #pragma unroll
            for (int r = 0; r < 4; r++) cst[s][mt][r] = cv;
    }

    const size_t orow = (size_t)T * F;
    const short* wl = wout_lds + w * 8192 + lane * 8;

    for (int t = 0; t < T; t++) {
        // gates = x_proj + h_t @ W_hh^T
        f32x4 acc[8][2];
        #pragma unroll
        for (int i = 0; i < 8; i++) { acc[i][0] = xpj[i][0]; acc[i][1] = xpj[i][1]; }
        gate_mm(acc, whh_w, hbuf, lane);

        __syncthreads();   // all waves done reading h_t from LDS

        // in-register LSTM cell update (fp32), h written straight to LDS
        #pragma unroll
        for (int s = 0; s < 2; s++)
          #pragma unroll
          for (int mt = 0; mt < 2; mt++)
            #pragma unroll
            for (int r = 0; r < 4; r++) {
                float ig = sigm(acc[0 + s][mt][r]);
                float fg = sigm(acc[2 + s][mt][r]);
                float gg = tanhx(acc[4 + s][mt][r]);
                float og = sigm(acc[6 + s][mt][r]);
                float c  = fg * cst[s][mt][r] + ig * gg;
                cst[s][mt][r] = c;
                // C-layout -> LDS row-major: row = mt*16 + quad*4 + r, col = 32w+16s+l15
                hbuf[(mt * 16 + quad * 4 + r) * SH + w * 32 + s * 16 + l15]
                    = f2bf(og * tanhx(c));
            }
        __syncthreads();   // h_{t+1} visible to all waves

        // fused output projection from LDS-resident W_out
        f32x4 oacc[2][2];
        #pragma unroll
        for (int s = 0; s < 2; s++) { oacc[s][0] = splat4(bo[s]); oacc[s][1] = splat4(bo[s]); }
        #pragma unroll
        for (int kt = 0; kt < 8; kt++) {
            short8 a0 = *(const short8*)(hbuf + l15 * SH + kt * 32 + quad * 8);
            short8 a1 = *(const short8*)(hbuf + (16 + l15) * SH + kt * 32 + quad * 8);
            #pragma unroll
            for (int s = 0; s < 2; s++) {
                short8 b = *(const short8*)(wl + kt * 1024 + s * 512);
                oacc[s][0] = __builtin_amdgcn_mfma_f32_16x16x32_bf16(a0, b, oacc[s][0], 0, 0, 0);
                oacc[s][1] = __builtin_amdgcn_mfma_f32_16x16x32_bf16(a1, b, oacc[s][1], 0, 0, 0);
            }
        }
        float* op = out + (size_t)row0 * orow + (size_t)t * F;
        #pragma unroll
        for (int s = 0; s < 2; s++)
          #pragma unroll
          for (int mt = 0; mt < 2; mt++)
            #pragma unroll
            for (int r = 0; r < 4; r++)
                __builtin_nontemporal_store(
                    oacc[s][mt][r],
                    &op[(size_t)(mt * 16 + quad * 4 + r) * orow + w * 32 + s * 16 + l15]);
    }
}

extern "C" void kernel_launch(void* const* d_in, const int* in_sizes, int n_in,
                              void* d_out, int out_size, void* d_ws, size_t ws_size,
                              hipStream_t stream)
{
    const float* x    = (const float*)d_in[0];
    const float* Wih  = (const float*)d_in[1];
    const float* Whh  = (const float*)d_in[2];
    const float* bih  = (const float*)d_in[3];
    const float* bhh  = (const float*)d_in[4];
    const float* c0   = (const float*)d_in[5];
    const float* Wout = (const float*)d_in[6];
    const float* bout = (const float*)d_in[7];
    const int* seqlen = (const int*)d_in[8];

    // workspace: packed weights (re-packed every launch; ws is re-poisoned)
    short* whh_p  = (short*)d_ws;            // 1024*256 bf16 = 512 KB
    short* wih_hi = whh_p  + 1024 * 256;     // 512 KB
    short* wih_lo = wih_hi + 1024 * 256;     // 512 KB
    short* wout_p = wih_lo + 1024 * 256;     // 256*256 bf16 = 128 KB
    (void)ws_size; (void)in_sizes; (void)n_in; (void)out_size;

    pack_kernel<<<160, 256, 0, stream>>>(Whh, Wih, Wout, whh_p, wih_hi, wih_lo, wout_p);
    lstm_fused<<<128, 512, 0, stream>>>(x, bih, bhh, c0, bout,
                                        whh_p, wih_hi, wih_lo, wout_p,
                                        seqlen, (float*)d_out);
}